// Round 10
// baseline (707.364 us; speedup 1.0000x reference)
//
#include <hip/hip_runtime.h>
#include <hip/hip_fp16.h>

#define NB 256      // batch
#define NT 1024     // time
#define ND 64       // input dim
#define NH 128      // hidden dim

typedef __fp16 half8 __attribute__((ext_vector_type(8)));
typedef __fp16 half4v __attribute__((ext_vector_type(4)));
typedef float float4v __attribute__((ext_vector_type(4)));

static __device__ __forceinline__ float fast_tanh(float v) {
    float e = __expf(2.0f * v);
    return 1.0f - 2.0f * __builtin_amdgcn_rcpf(e + 1.0f);
}

// lgkm-only barrier: does NOT drain vmcnt (stores / x prefetch keep flying)
static __device__ __forceinline__ void fast_barrier() {
    asm volatile("s_waitcnt lgkmcnt(0)\n\ts_barrier" ::: "memory");
}

// v10 = v8 skeleton x 2 independent batch chains per block (ILP stall-fill).
// 128 blocks x 512 threads (8 waves, 2/SIMD). Wave w owns hidden units
// j in [16w, 16w+16) for BOTH chains; lane l16 holds one j (kg duplicates 4x).
// Per step each chain: 4 ds_read_b128 (h broadcast) -> 4 MFMAs (2+2 chains,
// D col=l16 -> own j in reg 0, no select) -> sigmoid/tanh tail -> publish.
// The two chains are independent -> the compiler interleaves them statically,
// filling the ~300cy of exposed latency v8 could not hide (its 2 waves/SIMD
// are barrier-locked to the same phase). Weights shared across chains.
// Only sync: one lgkm barrier per step (both chains exchange at it).
__global__ __launch_bounds__(512, 2) void fused_rnn_v10(
        const float* __restrict__ x,
        const float* __restrict__ WxK, const float* __restrict__ bxK,
        const float* __restrict__ Wxz, const float* __restrict__ bxz,
        const float* __restrict__ Whk, const float* __restrict__ bhk,
        float* __restrict__ out) {
    __shared__ __align__(16) __fp16 hbufA[2][128], hbufB[2][128];
    __shared__ __align__(16) __fp16 gTA[2][128][24], gTB[2][128][24];  // (gxK+b)^T [j][s]
    __shared__ __align__(16) __fp16 zTA[2][128][24], zTB[2][128][24];  // tanh(gxz+b)^T

    const int tid = threadIdx.x;
    const int b0 = blockIdx.x * 2, b1 = b0 + 1;
    const int w = tid >> 6, lane = tid & 63;
    const int l16 = lane & 15, kg = lane >> 4;
    const int j = w * 16 + l16;              // this lane's hidden unit (both chains)

    // ---- W_hK^T B-fragments (shared): B[k=kt*32+kg*8+e][n=l16] = Whk[j][k] ----
    half8 whT[4];
    #pragma unroll
    for (int kt = 0; kt < 4; ++kt) {
        const float* p = Whk + (size_t)j * NH + kt * 32 + kg * 8;
        float4v u = *(const float4v*)p, v = *(const float4v*)(p + 4);
        whT[kt] = (half8){(__fp16)u.x, (__fp16)u.y, (__fp16)u.z, (__fp16)u.w,
                          (__fp16)v.x, (__fp16)v.y, (__fp16)v.z, (__fp16)v.w};
    }
    // ---- proj B-fragments (shared): rows of WxK / Wxz ----
    half8 wxT[2][2];   // [mat][kt]
    #pragma unroll
    for (int mat = 0; mat < 2; ++mat) {
        const float* W = mat ? Wxz : WxK;
        #pragma unroll
        for (int kt = 0; kt < 2; ++kt) {
            const float* p = W + (size_t)j * ND + kt * 32 + kg * 8;
            float4v u = *(const float4v*)p, v = *(const float4v*)(p + 4);
            wxT[mat][kt] = (half8){(__fp16)u.x, (__fp16)u.y, (__fp16)u.z, (__fp16)u.w,
                                   (__fp16)v.x, (__fp16)v.y, (__fp16)v.z, (__fp16)v.w};
        }
    }
    const float bGK = bxK[j] + bhk[j];
    const float bZ  = bxz[j];
    const float4v zero4 = {0.f, 0.f, 0.f, 0.f};

    const float* xbA = x + (size_t)b0 * NT * ND;
    const float* xbB = x + (size_t)b1 * NT * ND;
    float4v xfA[4], xfB[4];   // prefetched x chunks (A-fragments, f32)

    auto xload = [&](const float* xb, float4v (&xf)[4], int c) {
        const float* px = xb + (size_t)c * 16 * 64 + (size_t)l16 * 64;
        #pragma unroll
        for (int kt = 0; kt < 2; ++kt) {
            const float* qp = px + kt * 32 + kg * 8;
            xf[2 * kt]     = *(const float4v*)qp;
            xf[2 * kt + 1] = *(const float4v*)(qp + 4);
        }
    };

    // project one staged chunk into its chain's gT/zT[dst] rows (same-wave use,
    // barrier-free): 4 MFMAs + 2 packed b64 writes + 4 tanh
    auto proj = [&](float4v (&xf)[4], __fp16 (*gT)[128][24], __fp16 (*zT)[128][24], int dst) {
        half8 ax0, ax1;
        {
            float4v u0 = xf[0], v0 = xf[1], u1 = xf[2], v1 = xf[3];
            ax0 = (half8){(__fp16)u0.x, (__fp16)u0.y, (__fp16)u0.z, (__fp16)u0.w,
                          (__fp16)v0.x, (__fp16)v0.y, (__fp16)v0.z, (__fp16)v0.w};
            ax1 = (half8){(__fp16)u1.x, (__fp16)u1.y, (__fp16)u1.z, (__fp16)u1.w,
                          (__fp16)v1.x, (__fp16)v1.y, (__fp16)v1.z, (__fp16)v1.w};
        }
        float4v pg = __builtin_amdgcn_mfma_f32_16x16x32_f16(ax0, wxT[0][0], zero4, 0, 0, 0);
        pg = __builtin_amdgcn_mfma_f32_16x16x32_f16(ax1, wxT[0][1], pg, 0, 0, 0);
        half4v hg = {(__fp16)(pg[0] + bGK), (__fp16)(pg[1] + bGK),
                     (__fp16)(pg[2] + bGK), (__fp16)(pg[3] + bGK)};
        *(half4v*)&gT[dst][j][kg * 4] = hg;
        float4v pz = __builtin_amdgcn_mfma_f32_16x16x32_f16(ax0, wxT[1][0], zero4, 0, 0, 0);
        pz = __builtin_amdgcn_mfma_f32_16x16x32_f16(ax1, wxT[1][1], pz, 0, 0, 0);
        half4v hz = {(__fp16)fast_tanh(pz[0] + bZ), (__fp16)fast_tanh(pz[1] + bZ),
                     (__fp16)fast_tanh(pz[2] + bZ), (__fp16)fast_tanh(pz[3] + bZ)};
        *(half4v*)&zT[dst][j][kg * 4] = hz;
    };

    // ---- prologue ----
    xload(xbA, xfA, 0);
    xload(xbB, xfB, 0);
    if (tid < 128) {
        hbufA[0][tid] = (__fp16)0.0f;
        hbufB[0][tid] = (__fp16)0.0f;
    }
    proj(xfA, gTA, zTA, 0);
    proj(xfB, gTB, zTB, 0);
    xload(xbA, xfA, 1);
    xload(xbB, xfB, 1);
    __syncthreads();

    float hnA = 0.0f, hnB = 0.0f;
    float oregA[16], oregB[16];
    const size_t CPY = (size_t)NB * NT * NH;
    // kg 0/1 -> chain A copies 0/1; kg 2/3 -> chain B copies 0/1
    float* obase = out + (size_t)(kg < 2 ? b0 : b1) * NT * NH
                 + ((kg & 1) ? CPY : 0) + j;

    for (int c = 0; c < 64; ++c) {
        const int cb = c & 1;

        // hoist both chains' g/z for this chunk: 8x ds_read_b128, off the chain
        half8 gAa = *(const half8*)&gTA[cb][j][0], gAb = *(const half8*)&gTA[cb][j][8];
        half8 zAa = *(const half8*)&zTA[cb][j][0], zAb = *(const half8*)&zTA[cb][j][8];
        half8 gBa = *(const half8*)&gTB[cb][j][0], gBb = *(const half8*)&gTB[cb][j][8];
        half8 zBa = *(const half8*)&zTB[cb][j][0], zBb = *(const half8*)&zTB[cb][j][8];

        #pragma unroll
        for (int s = 0; s < 16; ++s) {
            const int p = s & 1;
            // h broadcast reads, both chains (addr depends only on kg) — 8x b128
            half8 aA0 = *(const half8*)&hbufA[p][0 * 32 + kg * 8];
            half8 aA1 = *(const half8*)&hbufA[p][1 * 32 + kg * 8];
            half8 aA2 = *(const half8*)&hbufA[p][2 * 32 + kg * 8];
            half8 aA3 = *(const half8*)&hbufA[p][3 * 32 + kg * 8];
            half8 aB0 = *(const half8*)&hbufB[p][0 * 32 + kg * 8];
            half8 aB1 = *(const half8*)&hbufB[p][1 * 32 + kg * 8];
            half8 aB2 = *(const half8*)&hbufB[p][2 * 32 + kg * 8];
            half8 aB3 = *(const half8*)&hbufB[p][3 * 32 + kg * 8];

            const float gvA = (float)(s < 8 ? gAa[s & 7] : gAb[s & 7]);
            const float zvA = (float)(s < 8 ? zAa[s & 7] : zAb[s & 7]);
            const float gvB = (float)(s < 8 ? gBa[s & 7] : gBb[s & 7]);
            const float zvB = (float)(s < 8 ? zBa[s & 7] : zBb[s & 7]);
            const float dA = zvA - hnA;
            const float dB = zvB - hnB;

            // chain A matvec: 4 MFMAs, two 2-deep chains; D col=l16 -> own j
            float4v mA0 = __builtin_amdgcn_mfma_f32_16x16x32_f16(aA0, whT[0], zero4, 0, 0, 0);
            float4v mA1 = __builtin_amdgcn_mfma_f32_16x16x32_f16(aA2, whT[2], zero4, 0, 0, 0);
            // chain B matvec interleaves into A's shadows
            float4v mB0 = __builtin_amdgcn_mfma_f32_16x16x32_f16(aB0, whT[0], zero4, 0, 0, 0);
            float4v mB1 = __builtin_amdgcn_mfma_f32_16x16x32_f16(aB2, whT[2], zero4, 0, 0, 0);
            mA0 = __builtin_amdgcn_mfma_f32_16x16x32_f16(aA1, whT[1], mA0, 0, 0, 0);
            mA1 = __builtin_amdgcn_mfma_f32_16x16x32_f16(aA3, whT[3], mA1, 0, 0, 0);
            mB0 = __builtin_amdgcn_mfma_f32_16x16x32_f16(aB1, whT[1], mB0, 0, 0, 0);
            mB1 = __builtin_amdgcn_mfma_f32_16x16x32_f16(aB3, whT[3], mB1, 0, 0, 0);

            const float yA = mA0[0] + mA1[0];
            const float yB = mB0[0] + mB1[0];

            // tails (independent)
            const float KA = __builtin_amdgcn_rcpf(1.0f + __expf(-(yA + gvA)));
            const float KB = __builtin_amdgcn_rcpf(1.0f + __expf(-(yB + gvB)));
            hnA = fast_tanh(__builtin_fmaf(KA, dA, hnA));
            hnB = fast_tanh(__builtin_fmaf(KB, dB, hnB));
            oregA[s] = hnA;
            oregB[s] = hnB;

            if (kg == 0) hbufA[p ^ 1][j] = (__fp16)hnA;   // publish chain A
            if (kg == 1) hbufB[p ^ 1][j] = (__fp16)hnB;   // publish chain B
            fast_barrier();                   // the ONLY sync (both chains)
        }

        // burst-flush outputs: every lane stores 16 floats (chain/copy by kg)
        {
            float* po = obase + (size_t)(c * 16) * NH;
            #pragma unroll
            for (int s = 0; s < 16; ++s) {
                *po = (kg < 2) ? oregA[s] : oregB[s];
                po += NH;
            }
        }

        // barrier-free proj of chunk c+1 for both chains, then prefetch c+2
        if (c < 63) {
            proj(xfA, gTA, zTA, cb ^ 1);
            proj(xfB, gTB, zTB, cb ^ 1);
            if (c < 62) {
                xload(xbA, xfA, c + 2);
                xload(xbB, xfB, c + 2);
            }
        }
    }
}

extern "C" void kernel_launch(void* const* d_in, const int* in_sizes, int n_in,
                              void* d_out, int out_size, void* d_ws, size_t ws_size,
                              hipStream_t stream) {
    (void)in_sizes; (void)n_in; (void)d_ws; (void)ws_size; (void)out_size;
    const float* x   = (const float*)d_in[0];
    const float* WxK = (const float*)d_in[1];
    const float* bxK = (const float*)d_in[2];
    const float* Wxz = (const float*)d_in[3];
    const float* bxz = (const float*)d_in[4];
    const float* Whk = (const float*)d_in[5];
    const float* bhk = (const float*)d_in[6];
    float* out = (float*)d_out;

    fused_rnn_v10<<<128, 512, 0, stream>>>(x, WxK, bxK, Wxz, bxz, Whk, bhk, out);
}